// Round 17
// baseline (359.315 us; speedup 1.0000x reference)
//
#include <hip/hip_runtime.h>
#include <hip/hip_bf16.h>

// MoE SwiGLU: H=2048, I=1408, E=8, TOPK=2, T=4096 tokens (8192 pairs).
// R17 = R15/R16 resubmitted unchanged (both died on infra: UnresponsiveContainer,
// same wedged container; kernel never executed).
// R15 = R14 with ONE change: gemm2 gets the T3 minimum 2-phase pipeline with
// FOUR NAMED LDS buffers (A0/B0/A1/B1, statically disjoint so the compiler can
// prove ds_read(cur) doesn't alias the just-issued global_load_lds(next) and
// emit no early vmcnt wait). BK=64 kept (R8's BK=32 sector-split confound
// removed). gemm1 untouched as control.

typedef __bf16 bf16;
typedef bf16 bf16x8 __attribute__((ext_vector_type(8)));
typedef float f32x4 __attribute__((ext_vector_type(4)));

constexpr int Hdim = 2048;
constexpr int Idim = 1408;
constexpr int NE = 8;
constexpr int TOPK = 2;
constexpr int NT = 4096;      // tokens
constexpr int NPAIR = 8192;   // T * TOPK
constexpr int BK = 64;

#define GLOAD16(G, L) __builtin_amdgcn_global_load_lds(                    \
    (const __attribute__((address_space(1))) void*)(G),                    \
    (__attribute__((address_space(3))) void*)(L), 16, 0, 0)

// ---------------- f32 -> bf16 convert (streaming) ----------------

__global__ void k_cvt(const float* __restrict__ src, bf16* __restrict__ dst, int n8) {
    int i = blockIdx.x * 256 + threadIdx.x;
    if (i >= n8) return;
    f32x4 a = *reinterpret_cast<const f32x4*>(src + (size_t)i * 8);
    f32x4 b = *reinterpret_cast<const f32x4*>(src + (size_t)i * 8 + 4);
    bf16x8 v;
#pragma unroll
    for (int j = 0; j < 4; j++) { v[j] = (bf16)a[j]; v[4 + j] = (bf16)b[j]; }
    *reinterpret_cast<bf16x8*>(dst + (size_t)i * 8) = v;
}

// ---------------- binning (deterministic) ----------------

__global__ void k_bin1(const int* __restrict__ eidx, int* __restrict__ chunkhist) {
    __shared__ int h[NE];
    int t = threadIdx.x;
    if (t < NE) h[t] = 0;
    __syncthreads();
    int p = blockIdx.x * 256 + t;
    atomicAdd(&h[eidx[p]], 1);
    __syncthreads();
    if (t < NE) chunkhist[blockIdx.x * NE + t] = h[t];
}

__global__ void k_bin2(int* __restrict__ meta, const int* __restrict__ chunkhist,
                       int* __restrict__ chunkbase) {
    if (threadIdx.x == 0) {
        int counts[NE];
        for (int e = 0; e < NE; e++) counts[e] = 0;
        for (int b = 0; b < 32; b++)
            for (int e = 0; e < NE; e++) {
                chunkbase[b * NE + e] = counts[e];
                counts[e] += chunkhist[b * NE + e];
            }
        int acc = 0;
        for (int e = 0; e < NE; e++) {
            meta[e] = counts[e];      // counts
            meta[8 + e] = acc;        // exclusive offsets
            acc += counts[e];
        }
    }
}

__global__ void k_bin3(const int* __restrict__ eidx, const float* __restrict__ wts,
                       const int* __restrict__ meta, const int* __restrict__ chunkbase,
                       int* __restrict__ token_id, float* __restrict__ weightv) {
    __shared__ int earr[256];
    int t = threadIdx.x;
    int p = blockIdx.x * 256 + t;
    int e = eidx[p];
    earr[t] = e;
    __syncthreads();
    int rank = 0;
    for (int q = 0; q < t; q++) rank += (earr[q] == e) ? 1 : 0;
    int pos = meta[8 + e] + chunkbase[blockIdx.x * NE + e] + rank;
    token_id[pos] = p / TOPK;
    weightv[pos] = wts[p];
}

// ---------------- GEMM1: gu = X_e * w13[e]^T, fused SwiGLU (R7/R14 verbatim) ----------------
// Flat grid 1408 = 16 m-slots x 11 y-tiles x 8 experts. XCD-chunk swizzle:
// work = (flat%8)*176 + flat/8; grp = work>>4 in [11k, 11k+11) on XCD k.

__global__ __launch_bounds__(256, 2) void k_gemm1(
    const bf16* __restrict__ xb, const bf16* __restrict__ w13b,
    const int* __restrict__ meta, bf16* __restrict__ hact) {
    const int flat = blockIdx.x;
    const int work = (flat & 7) * 176 + (flat >> 3);
    const int mslot = work & 15;
    const int grp = work >> 4;        // [0,88)
    const int e = grp / 11;
    const int ytile = grp - e * 11;

    const int n_e = meta[e];
    const int m0 = mslot * 128;
    if (m0 >= n_e) return;
    const int base = meta[8 + e];
    const int* toks = (const int*)(meta + 64) + base;
    const bf16* wg = w13b + (size_t)e * (2 * Idim) * Hdim + (size_t)(ytile * 128) * Hdim;
    const bf16* wu = wg + (size_t)Idim * Hdim;

    __shared__ bf16 As[128 * 64];
    __shared__ bf16 Bg[128 * 64];
    __shared__ bf16 Bu[128 * 64];

    const int tid = threadIdx.x;
    const int lane = tid & 63;
    const int wid = tid >> 6;
    const int wr = wid >> 1, wc = wid & 1;
    const int l16 = lane & 15, lq = lane >> 4;

    // staging: 1024 slots of 16B per tile, 4 rounds x 256 threads.
    // LDS dest LINEAR; global source pre-swizzled: LDS seg s of row r holds
    // global seg s^(r&7).
    const bf16* gA[4];
    const bf16* gG[4];
    const bf16* gU[4];
    int lo[4];
#pragma unroll
    for (int r = 0; r < 4; r++) {
        int sid = r * 256 + tid;
        int row = sid >> 3, seg = sid & 7;
        int ss = seg ^ (row & 7);
        lo[r] = (r * 256 + (tid & ~63)) * 16;   // wave-uniform LDS byte base
        int rr = m0 + row;
        if (rr >= n_e) rr = n_e - 1;            // clamp keeps reads in-bounds
        gA[r] = xb + (size_t)toks[rr] * Hdim + ss * 8;
        gG[r] = wg + (size_t)row * Hdim + ss * 8;
        gU[r] = wu + (size_t)row * Hdim + ss * 8;
    }

    f32x4 accg[4][4], accu[4][4];
#pragma unroll
    for (int m = 0; m < 4; m++)
#pragma unroll
        for (int n = 0; n < 4; n++) {
            accg[m][n] = f32x4{0.f, 0.f, 0.f, 0.f};
            accu[m][n] = f32x4{0.f, 0.f, 0.f, 0.f};
        }

    for (int k0 = 0; k0 < Hdim; k0 += BK) {
        __syncthreads();
#pragma unroll
        for (int r = 0; r < 4; r++) {
            GLOAD16(gA[r] + k0, (char*)As + lo[r]);
            GLOAD16(gG[r] + k0, (char*)Bg + lo[r]);
            GLOAD16(gU[r] + k0, (char*)Bu + lo[r]);
        }
        __syncthreads();
#pragma unroll
        for (int kk = 0; kk < 2; ++kk) {
            bf16x8 af[4], bgf[4], buf_[4];
#pragma unroll
            for (int m = 0; m < 4; m++) {
                int row = wr * 64 + m * 16 + l16;
                int s = (kk * 4 + lq) ^ (row & 7);
                af[m] = *reinterpret_cast<const bf16x8*>(&As[row * 64 + s * 8]);
            }
#pragma unroll
            for (int n = 0; n < 4; n++) {
                int row = wc * 64 + n * 16 + l16;
                int s = (kk * 4 + lq) ^ (row & 7);
                bgf[n] = *reinterpret_cast<const bf16x8*>(&Bg[row * 64 + s * 8]);
                buf_[n] = *reinterpret_cast<const bf16x8*>(&Bu[row * 64 + s * 8]);
            }
#pragma unroll
            for (int m = 0; m < 4; m++)
#pragma unroll
                for (int n = 0; n < 4; n++) {
                    accg[m][n] = __builtin_amdgcn_mfma_f32_16x16x32_bf16(af[m], bgf[n], accg[m][n], 0, 0, 0);
                    accu[m][n] = __builtin_amdgcn_mfma_f32_16x16x32_bf16(af[m], buf_[n], accu[m][n], 0, 0, 0);
                }
        }
    }

    // epilogue: silu(g)*u -> hact. C layout: col=lane&15, row=(lane>>4)*4+reg
    const int colbase = ytile * 128 + wc * 64;
#pragma unroll
    for (int m = 0; m < 4; m++) {
        int lr0 = m0 + wr * 64 + m * 16 + lq * 4;
#pragma unroll
        for (int j = 0; j < 4; j++) {
            int lr = lr0 + j;
            if (lr < n_e) {
                size_t rowoff = (size_t)(base + lr) * Idim;
#pragma unroll
                for (int n = 0; n < 4; n++) {
                    float g = accg[m][n][j], u = accu[m][n][j];
                    float v = (g / (1.f + __expf(-g))) * u;
                    hact[rowoff + colbase + n * 16 + l16] = (bf16)v;
                }
            }
        }
    }
}

// ---------------- GEMM2: y = hact * down_proj[e]^T, weighted scatter-add ----------------
// 128x128 tile, BK=64. T3 minimum 2-phase: named dbuf A0/B0/A1/B1 (4 x 16KB),
// STAGE(next) issued before ds_read+MFMA(cur), one __syncthreads per phase.
// Flat grid 2048 = 16 m-slots x 16 y-tiles x 8 experts; XCD-chunk swizzle.

__global__ __launch_bounds__(256, 2) void k_gemm2(
    const bf16* __restrict__ hact, const bf16* __restrict__ dpb,
    const int* __restrict__ meta, const float* __restrict__ weightv,
    float* __restrict__ out) {
    const int flat = blockIdx.x;
    const int work = (flat & 7) * 256 + (flat >> 3);
    const int mslot = work & 15;
    const int grp = work >> 4;        // [0,128)
    const int e = grp >> 4;
    const int ytile = grp & 15;

    const int n_e = meta[e];
    const int m0 = mslot * 128;
    if (m0 >= n_e) return;
    const int base = meta[8 + e];
    const int* toks = (const int*)(meta + 64) + base;
    const bf16* wb = dpb + (size_t)e * Hdim * Idim + (size_t)(ytile * 128) * Idim;

    // four distinct objects -> static disjointness for alias analysis
    __shared__ bf16 A0[128 * 64];
    __shared__ bf16 B0[128 * 64];
    __shared__ bf16 A1[128 * 64];
    __shared__ bf16 B1[128 * 64];

    const int tid = threadIdx.x;
    const int lane = tid & 63;
    const int wid = tid >> 6;
    const int wr = wid >> 1, wc = wid & 1;
    const int l16 = lane & 15, lq = lane >> 4;

    const bf16* gA[4];
    const bf16* gB[4];
    int lo[4];
#pragma unroll
    for (int r = 0; r < 4; r++) {
        int sid = r * 256 + tid;
        int row = sid >> 3, seg = sid & 7;
        int ss = seg ^ (row & 7);
        lo[r] = (r * 256 + (tid & ~63)) * 16;
        int rr = m0 + row;
        if (rr >= n_e) rr = n_e - 1;
        gA[r] = hact + (size_t)(base + rr) * Idim + ss * 8;
        gB[r] = wb + (size_t)row * Idim + ss * 8;
    }

    f32x4 acc[4][4];
#pragma unroll
    for (int m = 0; m < 4; m++)
#pragma unroll
        for (int n = 0; n < 4; n++) acc[m][n] = f32x4{0.f, 0.f, 0.f, 0.f};

#define STG2(AB, BB, K0)                                                    \
    {                                                                       \
        _Pragma("unroll")                                                   \
        for (int r = 0; r < 4; r++) {                                       \
            GLOAD16(gA[r] + (K0), (char*)(AB) + lo[r]);                     \
            GLOAD16(gB[r] + (K0), (char*)(BB) + lo[r]);                     \
        }                                                                   \
    }

#define CMP2(AB, BB)                                                        \
    {                                                                       \
        _Pragma("unroll")                                                   \
        for (int kk = 0; kk < 2; ++kk) {                                    \
            bf16x8 af[4], bf_[4];                                           \
            _Pragma("unroll")                                               \
            for (int m = 0; m < 4; m++) {                                   \
                int row = wr * 64 + m * 16 + l16;                           \
                int s = (kk * 4 + lq) ^ (row & 7);                          \
                af[m] = *reinterpret_cast<const bf16x8*>(&(AB)[row * 64 + s * 8]); \
            }                                                               \
            _Pragma("unroll")                                               \
            for (int n = 0; n < 4; n++) {                                   \
                int row = wc * 64 + n * 16 + l16;                           \
                int s = (kk * 4 + lq) ^ (row & 7);                          \
                bf_[n] = *reinterpret_cast<const bf16x8*>(&(BB)[row * 64 + s * 8]); \
            }                                                               \
            _Pragma("unroll")                                               \
            for (int m = 0; m < 4; m++)                                     \
                _Pragma("unroll")                                           \
                for (int n = 0; n < 4; n++)                                 \
                    acc[m][n] = __builtin_amdgcn_mfma_f32_16x16x32_bf16(af[m], bf_[n], acc[m][n], 0, 0, 0); \
        }                                                                   \
    }

    // prologue: tile 0 -> buf0
    STG2(A0, B0, 0);
    __syncthreads();
    // 22 K-steps, unrolled x2: phase A computes even tiles (buf0), phase B odd (buf1)
    for (int t = 0; t < Idim / BK; t += 2) {
        STG2(A1, B1, (t + 1) * BK);           // next-tile loads fly under MFMA
        CMP2(A0, B0);
        __syncthreads();                       // drains buf1 loads + barrier
        if (t + 2 < Idim / BK) STG2(A0, B0, (t + 2) * BK);
        CMP2(A1, B1);
        __syncthreads();
    }

    const int colbase = ytile * 128 + wc * 64;
#pragma unroll
    for (int m = 0; m < 4; m++) {
        int lr0 = m0 + wr * 64 + m * 16 + lq * 4;
#pragma unroll
        for (int j = 0; j < 4; j++) {
            int lr = lr0 + j;
            if (lr < n_e) {
                int tok = toks[lr];
                float w = weightv[base + lr];
#pragma unroll
                for (int n = 0; n < 4; n++) {
                    float v = acc[m][n][j] * w;
                    unsafeAtomicAdd(&out[(size_t)tok * Hdim + colbase + n * 16 + l16], v);
                }
            }
        }
    }
#undef STG2
#undef CMP2
}

// ---------------- launch ----------------

extern "C" void kernel_launch(void* const* d_in, const int* in_sizes, int n_in,
                              void* d_out, int out_size, void* d_ws, size_t ws_size,
                              hipStream_t stream) {
    const float* x = (const float*)d_in[0];
    const int* eidx = (const int*)d_in[1];
    const float* ewts = (const float*)d_in[2];
    const float* w13 = (const float*)d_in[3];
    const float* dproj = (const float*)d_in[4];
    float* out = (float*)d_out;

    // ws layout (bytes): ints block [0, 67840), then bf16 buffers (16B-aligned)
    char* ws = (char*)d_ws;
    int* meta = (int*)ws;                       // [0..7] counts, [8..15] offsets
    int* token_id = meta + 64;                  // [NPAIR]
    float* weightv = (float*)(meta + 64 + NPAIR);
    int* chunkhist = meta + 64 + 2 * NPAIR;     // [32*NE]
    int* chunkbase = chunkhist + 256;           // [32*NE]
    bf16* xb = (bf16*)(ws + 67840);             // [NT][Hdim]
    bf16* w13b = xb + (size_t)NT * Hdim;        // [NE][2*Idim][Hdim]
    bf16* dpb = w13b + (size_t)NE * 2 * Idim * Hdim;  // [NE][Hdim][Idim]
    bf16* hact = dpb + (size_t)NE * Hdim * Idim;      // [NPAIR][Idim]

    hipMemsetAsync(d_out, 0, (size_t)out_size * sizeof(float), stream);

    const int nx8 = NT * Hdim / 8;                    // 1048576
    const int nw8 = NE * 2 * Idim * Hdim / 8;         // 5767168
    const int nd8 = NE * Hdim * Idim / 8;             // 2883584
    k_cvt<<<(nx8 + 255) / 256, 256, 0, stream>>>(x, xb, nx8);
    k_cvt<<<(nw8 + 255) / 256, 256, 0, stream>>>(w13, w13b, nw8);
    k_cvt<<<(nd8 + 255) / 256, 256, 0, stream>>>(dproj, dpb, nd8);

    k_bin1<<<32, 256, 0, stream>>>(eidx, chunkhist);
    k_bin2<<<1, 64, 0, stream>>>(meta, chunkhist, chunkbase);
    k_bin3<<<32, 256, 0, stream>>>(eidx, ewts, meta, chunkbase, token_id, weightv);

    k_gemm1<<<1408, 256, 0, stream>>>(xb, w13b, meta, hact);
    k_gemm2<<<2048, 256, 0, stream>>>(hact, dpb, meta, weightv, out);
}